// Round 2
// baseline (3107.570 us; speedup 1.0000x reference)
//
#include <hip/hip_runtime.h>
#include <hip/hip_bf16.h>

typedef __hip_bfloat16 bf16;

#define B_   2
#define T_   2048
#define D_   512
#define H_   8
#define DK_  64
#define DFF_ 2048
#define M_   (B_*T_)   // 4096 rows

static __device__ __forceinline__ float b2f(bf16 v) { return __bfloat162float(v); }
static __device__ __forceinline__ bf16  f2b(float v){ return __float2bfloat16(v); }

// Flagged load/store: bf==true -> buffer is bf16, else fp32.
static __device__ __forceinline__ float ldin(const void* p, size_t i, bool bf) {
    return bf ? __bfloat162float(((const bf16*)p)[i]) : ((const float*)p)[i];
}
static __device__ __forceinline__ void stout(void* p, size_t i, float v, bool bf) {
    if (bf) ((bf16*)p)[i] = __float2bfloat16(v);
    else    ((float*)p)[i] = v;
}

// ---------------------------------------------------------------------------
// Dtype detector: if x is bf16, the low 16 bits of each 32-bit word are a
// bf16 value of ~N(0,1) data -> |v| in (1e-3, 16) almost surely. If x is
// fp32, the low 16 bits are ~uniform mantissa bits -> in-range ~5%.
// flag=1 -> bf16, flag=0 -> fp32.
// ---------------------------------------------------------------------------
__global__ void detect_dtype(const unsigned int* __restrict__ x, int* __restrict__ flag)
{
    if (threadIdx.x == 0 && blockIdx.x == 0) {
        int inr = 0;
        for (int i = 0; i < 1024; ++i) {
            unsigned int lo = x[i] & 0xFFFFu;
            float v = __uint_as_float(lo << 16);
            float a = fabsf(v);
            if (a > 1e-3f && a < 16.f) inr++;
        }
        *flag = (inr > 512) ? 1 : 0;
    }
}

// ---------------------------------------------------------------------------
// Tiled GEMM: C[M,N] = A[M,K] @ B[K,N] + bias, optional ReLU.
// AFLAG=1: A dtype follows *flag; AFLAG=0: A is fp32 (workspace).
// Bm/bias dtype always follows *flag (model weights). C fp32.
// 64x64 tile, 256 threads, 4x4 micro-tile, K-step 16.
// ---------------------------------------------------------------------------
template<int AFLAG, int RELU>
__global__ __launch_bounds__(256)
void gemm_tiled(const void* A, const void* Bm, const void* bias,
                const int* __restrict__ flag, float* __restrict__ C,
                int M, int N, int K)
{
    const bool bfw = (*flag != 0);
    const bool bfa = AFLAG ? bfw : false;

    __shared__ float As[64][17];
    __shared__ float Bs[16][68];

    const int tid = threadIdx.x;
    const int tx  = tid & 15;
    const int ty  = tid >> 4;
    const int rowBase = blockIdx.y * 64;
    const int colBase = blockIdx.x * 64;

    float acc[4][4] = {};

    for (int k0 = 0; k0 < K; k0 += 16) {
        #pragma unroll
        for (int l = 0; l < 4; ++l) {            // A tile: 64x16
            int idx = tid + l * 256;
            int m = idx >> 4, kk = idx & 15;
            As[m][kk] = ldin(A, (size_t)(rowBase + m) * K + k0 + kk, bfa);
        }
        #pragma unroll
        for (int l = 0; l < 4; ++l) {            // B tile: 16x64
            int idx = tid + l * 256;
            int kk = idx >> 6, n = idx & 63;
            Bs[kk][n] = ldin(Bm, (size_t)(k0 + kk) * N + colBase + n, bfw);
        }
        __syncthreads();

        #pragma unroll
        for (int kk = 0; kk < 16; ++kk) {
            float a0 = As[ty*4+0][kk], a1 = As[ty*4+1][kk];
            float a2 = As[ty*4+2][kk], a3 = As[ty*4+3][kk];
            float b0 = Bs[kk][tx*4+0], b1 = Bs[kk][tx*4+1];
            float b2 = Bs[kk][tx*4+2], b3 = Bs[kk][tx*4+3];
            acc[0][0] += a0*b0; acc[0][1] += a0*b1; acc[0][2] += a0*b2; acc[0][3] += a0*b3;
            acc[1][0] += a1*b0; acc[1][1] += a1*b1; acc[1][2] += a1*b2; acc[1][3] += a1*b3;
            acc[2][0] += a2*b0; acc[2][1] += a2*b1; acc[2][2] += a2*b2; acc[2][3] += a2*b3;
            acc[3][0] += a3*b0; acc[3][1] += a3*b1; acc[3][2] += a3*b2; acc[3][3] += a3*b3;
        }
        __syncthreads();
    }

    float bv[4];
    #pragma unroll
    for (int j = 0; j < 4; ++j) bv[j] = ldin(bias, colBase + tx*4 + j, bfw);

    #pragma unroll
    for (int i = 0; i < 4; ++i) {
        #pragma unroll
        for (int j = 0; j < 4; ++j) {
            float v = acc[i][j] + bv[j];
            if (RELU) v = fmaxf(v, 0.f);
            C[(size_t)(rowBase + ty*4 + i) * N + colBase + tx*4 + j] = v;
        }
    }
}

// ---------------------------------------------------------------------------
// Attention: block = (b, h, 16-row q tile). Two passes over keys:
//   pass A: online max/denominator (no storage)
//   pass B: recompute scores, write attn probs to d_out (+M*D offset),
//           accumulate ctx.
// ---------------------------------------------------------------------------
__global__ __launch_bounds__(256)
void attn_kernel(const float* __restrict__ Q, const float* __restrict__ K,
                 const float* __restrict__ V, void* dout,
                 const int* __restrict__ flag, float* __restrict__ ctx)
{
    const bool bf = (*flag != 0);
    const int tid = threadIdx.x;
    const int qi  = tid >> 4;
    const int ki  = tid & 15;
    const int q0  = blockIdx.x * 16;
    const int h   = blockIdx.y;
    const int b   = blockIdx.z;
    const size_t OFFOUT = (size_t)M_ * D_;

    __shared__ float Qs[16][65];
    __shared__ float Ks[16][65];
    __shared__ float Vs[16][65];
    __shared__ float Ps[16][17];

    const float scale = 0.125f;     // 1/sqrt(64)
    #pragma unroll
    for (int l = 0; l < 4; ++l) {
        int idx = tid + l * 256;
        int r = idx >> 6, d = idx & 63;
        Qs[r][d] = Q[(size_t)(b*T_ + q0 + r) * D_ + h*DK_ + d] * scale;
    }
    __syncthreads();

    // ---- pass A ----
    float m = -1e30f, lsum = 0.f;
    for (int kt = 0; kt < T_/16; ++kt) {
        #pragma unroll
        for (int l = 0; l < 4; ++l) {
            int idx = tid + l * 256;
            int r = idx >> 6, d = idx & 63;
            Ks[r][d] = K[(size_t)(b*T_ + kt*16 + r) * D_ + h*DK_ + d];
        }
        __syncthreads();

        float s = 0.f;
        #pragma unroll
        for (int t = 0; t < 64; ++t) s += Qs[qi][t] * Ks[ki][t];

        float tm = s;
        #pragma unroll
        for (int o = 8; o; o >>= 1) tm = fmaxf(tm, __shfl_xor(tm, o, 16));
        float nm = fmaxf(m, tm);
        float ex = __expf(s - nm);
        float ts = ex;
        #pragma unroll
        for (int o = 8; o; o >>= 1) ts += __shfl_xor(ts, o, 16);
        lsum = lsum * __expf(m - nm) + ts;
        m = nm;
        __syncthreads();
    }
    const float inv_l = 1.f / lsum;

    // ---- pass B ----
    float a0 = 0.f, a1 = 0.f, a2 = 0.f, a3 = 0.f;
    const size_t arow = (size_t)((b*H_ + h)*T_ + q0 + qi) * T_;

    for (int kt = 0; kt < T_/16; ++kt) {
        #pragma unroll
        for (int l = 0; l < 4; ++l) {
            int idx = tid + l * 256;
            int r = idx >> 6, d = idx & 63;
            size_t g = (size_t)(b*T_ + kt*16 + r) * D_ + h*DK_ + d;
            Ks[r][d] = K[g];
            Vs[r][d] = V[g];
        }
        __syncthreads();

        float s = 0.f;
        #pragma unroll
        for (int t = 0; t < 64; ++t) s += Qs[qi][t] * Ks[ki][t];
        float p = __expf(s - m) * inv_l;
        if (bf) ((bf16*)dout)[OFFOUT + arow + kt*16 + ki] = f2b(p);
        else    ((float*)dout)[OFFOUT + arow + kt*16 + ki] = p;
        Ps[qi][ki] = p;
        __syncthreads();

        #pragma unroll
        for (int kk = 0; kk < 16; ++kk) {
            float pv = Ps[qi][kk];
            a0 += pv * Vs[kk][ki*4+0];
            a1 += pv * Vs[kk][ki*4+1];
            a2 += pv * Vs[kk][ki*4+2];
            a3 += pv * Vs[kk][ki*4+3];
        }
        __syncthreads();
    }

    float* crow = ctx + (size_t)(b*T_ + q0 + qi) * D_ + h*DK_ + ki*4;
    crow[0] = a0; crow[1] = a1; crow[2] = a2; crow[3] = a3;
}

// ---------------------------------------------------------------------------
// LN1: h = LayerNorm(x + attn_out) * g + b -> fp32. out may alias A (in-place:
// all reads of A happen before the barrier, all writes after).
// ---------------------------------------------------------------------------
__global__ __launch_bounds__(256)
void ln1_kernel(const void* X, const float* __restrict__ A,
                const void* g, const void* be,
                const int* __restrict__ flag, float* __restrict__ out)
{
    const bool bf = (*flag != 0);
    const int row = blockIdx.x;
    const int tid = threadIdx.x;
    const size_t base = (size_t)row * D_;

    float v0 = ldin(X, base + tid, bf)       + A[base + tid];
    float v1 = ldin(X, base + 256 + tid, bf) + A[base + 256 + tid];
    float s  = v0 + v1;
    float sq = v0*v0 + v1*v1;
    #pragma unroll
    for (int o = 32; o; o >>= 1) { s += __shfl_xor(s, o, 64); sq += __shfl_xor(sq, o, 64); }

    __shared__ float rs[4], rq[4];
    if ((tid & 63) == 0) { rs[tid >> 6] = s; rq[tid >> 6] = sq; }
    __syncthreads();
    s  = rs[0] + rs[1] + rs[2] + rs[3];
    sq = rq[0] + rq[1] + rq[2] + rq[3];

    float mu   = s * (1.f / D_);
    float var  = sq * (1.f / D_) - mu * mu;
    float rstd = rsqrtf(var + 1e-5f);
    out[base + tid]       = (v0 - mu) * rstd * ldin(g, tid, bf)       + ldin(be, tid, bf);
    out[base + 256 + tid] = (v1 - mu) * rstd * ldin(g, 256 + tid, bf) + ldin(be, 256 + tid, bf);
}

// ---------------------------------------------------------------------------
// LN2: out = LayerNorm(h + ffn2) * g + b -> d_out (dtype per flag)
// ---------------------------------------------------------------------------
__global__ __launch_bounds__(256)
void ln2_kernel(const float* __restrict__ Hf, const float* __restrict__ F,
                const void* g, const void* be,
                const int* __restrict__ flag, void* out)
{
    const bool bf = (*flag != 0);
    const int row = blockIdx.x;
    const int tid = threadIdx.x;
    const size_t base = (size_t)row * D_;

    float v0 = Hf[base + tid]       + F[base + tid];
    float v1 = Hf[base + 256 + tid] + F[base + 256 + tid];
    float s  = v0 + v1;
    float sq = v0*v0 + v1*v1;
    #pragma unroll
    for (int o = 32; o; o >>= 1) { s += __shfl_xor(s, o, 64); sq += __shfl_xor(sq, o, 64); }

    __shared__ float rs[4], rq[4];
    if ((tid & 63) == 0) { rs[tid >> 6] = s; rq[tid >> 6] = sq; }
    __syncthreads();
    s  = rs[0] + rs[1] + rs[2] + rs[3];
    sq = rq[0] + rq[1] + rq[2] + rq[3];

    float mu   = s * (1.f / D_);
    float var  = sq * (1.f / D_) - mu * mu;
    float rstd = rsqrtf(var + 1e-5f);
    stout(out, base + tid,       (v0 - mu) * rstd * ldin(g, tid, bf)       + ldin(be, tid, bf),       bf);
    stout(out, base + 256 + tid, (v1 - mu) * rstd * ldin(g, 256 + tid, bf) + ldin(be, 256 + tid, bf), bf);
}

// ---------------------------------------------------------------------------
extern "C" void kernel_launch(void* const* d_in, const int* in_sizes, int n_in,
                              void* d_out, int out_size, void* d_ws, size_t ws_size,
                              hipStream_t stream)
{
    const void* x     = d_in[0];
    const void* wq_w  = d_in[1];
    const void* wq_b  = d_in[2];
    const void* wk_w  = d_in[3];
    const void* wk_b  = d_in[4];
    const void* wv_w  = d_in[5];
    const void* wv_b  = d_in[6];
    const void* wo_w  = d_in[7];
    const void* wo_b  = d_in[8];
    const void* ln1_g = d_in[9];
    const void* ln1_b = d_in[10];
    const void* fc1_w = d_in[11];
    const void* fc1_b = d_in[12];
    const void* fc2_w = d_in[13];
    const void* fc2_b = d_in[14];
    const void* ln2_g = d_in[15];
    const void* ln2_b = d_in[16];

    // fp32 workspace, 6 slots of SL + flag: ~50.4 MB
    float* ws       = (float*)d_ws;
    const size_t SL = (size_t)M_ * D_;               // 2,097,152
    float* Q        = ws;                            // slot 0
    float* Kp       = Q  + SL;                       // slot 1
    float* V        = Kp + SL;                       // slot 2
    float* ctx      = V  + SL;                       // slot 3
    float* h        = ctx + SL;                      // slot 4 (attn_out, then h in-place)
    float* ffn2     = h + SL;                        // slot 5
    float* ffn1     = Q;                             // slots 0-3 exactly: [4096,2048]
    int*   flag     = (int*)(ffn2 + SL);

    dim3 blk(256);

    detect_dtype<<<1, 64, 0, stream>>>((const unsigned int*)x, flag);

    // QKV projections (A = x follows flag)
    gemm_tiled<1,0><<<dim3(D_/64,  M_/64), blk, 0, stream>>>(x, wq_w, wq_b, flag, Q,  M_, D_, D_);
    gemm_tiled<1,0><<<dim3(D_/64,  M_/64), blk, 0, stream>>>(x, wk_w, wk_b, flag, Kp, M_, D_, D_);
    gemm_tiled<1,0><<<dim3(D_/64,  M_/64), blk, 0, stream>>>(x, wv_w, wv_b, flag, V,  M_, D_, D_);

    // attention: writes probs into d_out (+M*D) and fp32 ctx
    attn_kernel<<<dim3(T_/16, H_, B_), blk, 0, stream>>>(Q, Kp, V, d_out, flag, ctx);

    // output projection (A = ctx fp32)
    gemm_tiled<0,0><<<dim3(D_/64,  M_/64), blk, 0, stream>>>(ctx, wo_w, wo_b, flag, h, M_, D_, D_);

    // residual + LN1 (in-place over attn_out)
    ln1_kernel<<<M_, 256, 0, stream>>>(x, h, ln1_g, ln1_b, flag, h);

    // FFN
    gemm_tiled<0,1><<<dim3(DFF_/64, M_/64), blk, 0, stream>>>(h,    fc1_w, fc1_b, flag, ffn1, M_, DFF_, D_);
    gemm_tiled<0,0><<<dim3(D_/64,   M_/64), blk, 0, stream>>>(ffn1, fc2_w, fc2_b, flag, ffn2, M_, D_, DFF_);

    // residual + LN2 -> d_out
    ln2_kernel<<<M_, 256, 0, stream>>>(h, ffn2, ln2_g, ln2_b, flag, d_out);
}